// Round 17
// baseline (342.630 us; speedup 1.0000x reference)
//
#include <hip/hip_runtime.h>

#define DIM   64
#define NROWS 65536
#define NCODE 1024
#define RPB   32
#define NBLK  (NROWS / RPB)   // 2048 blocks x 256 thr -> 8 blocks/CU, 32 waves/CU

typedef float    f32x4 __attribute__((ext_vector_type(4)));
typedef _Float16 f16x8 __attribute__((ext_vector_type(8)));

union U4H { uint4 u; f16x8 h; };

// fp32 = h + r, h = RNE fp16; r exact (Sterbenz); l = RNE fp16 of r.
__device__ __forceinline__ void split2(float f, unsigned short& hb,
                                       unsigned short& lb) {
  _Float16 h = (_Float16)f;
  float r = f - (float)h;
  _Float16 lo = (_Float16)r;
  hb = __builtin_bit_cast(unsigned short, h);
  lb = __builtin_bit_cast(unsigned short, lo);
}
__device__ __forceinline__ uint4 pack8(const unsigned short* p) {
  return make_uint4((unsigned)p[0] | ((unsigned)p[1] << 16),
                    (unsigned)p[2] | ((unsigned)p[3] << 16),
                    (unsigned)p[4] | ((unsigned)p[5] << 16),
                    (unsigned)p[6] | ((unsigned)p[7] << 16));
}

// ---- pre-pass: e -> fp16 (h,l) B-fragments + e2/2; also zeroes loss ----
// tile gt (16 codes): 4 frags [kh0_h, kh0_l, kh1_h, kh1_l] x 512 shorts,
// each frag lane-linear: lane l owns shorts [l*8, l*8+8).
__global__ __launch_bounds__(256) void vq_esplit(const float* __restrict__ e,
                                                 unsigned short* __restrict__ eB,
                                                 float* __restrict__ e2h,
                                                 float* __restrict__ loss) {
  const int c = blockIdx.x * 256 + threadIdx.x;   // code 0..1023
  if (c == 0) *loss = 0.f;                        // stream-ordered before vq_main
  const int gt = c >> 4, cl = c & 15;
  float s = 0.f;
  #pragma unroll
  for (int kh = 0; kh < 2; ++kh) {
    #pragma unroll
    for (int g = 0; g < 4; ++g) {
      const float* ep = e + (size_t)c * DIM + kh * 32 + g * 8;
      float4 v0 = *(const float4*)ep;
      float4 v1 = *(const float4*)(ep + 4);
      float f[8] = {v0.x, v0.y, v0.z, v0.w, v1.x, v1.y, v1.z, v1.w};
      unsigned short hb[8], lb[8];
      #pragma unroll
      for (int j = 0; j < 8; ++j) {
        split2(f[j], hb[j], lb[j]);
        s = fmaf(f[j], f[j], s);
      }
      const size_t pos = (size_t)((g << 4) | cl) * 8;
      const size_t tb = (size_t)gt * 2048;
      *(uint4*)(eB + tb + (kh * 2 + 0) * 512 + pos) = pack8(hb);
      *(uint4*)(eB + tb + (kh * 2 + 1) * 512 + pos) = pack8(lb);
    }
  }
  e2h[c] = 0.5f * s;
}

// ---- main: barrier-free loop at MAX occupancy. Block = 32 rows, 4 waves;
// wave wv scans code quarter [wv*256, wv*256+256) global->register with
// 1-tile rotate prefetch and per-wave phase. 8192 waves -> 32 waves/CU. ----
__global__ __launch_bounds__(256, 8) void vq_main(
    const float* __restrict__ x,
    const float* __restrict__ e,
    const unsigned short* __restrict__ eB,
    const float* __restrict__ e2h,
    float* __restrict__ out,
    float* __restrict__ loss)
{
  __shared__ __align__(16) float e2L[NCODE];   // 4 KB
  __shared__ float bestL[4][RPB];
  __shared__ int   kL[4][RPB];
  __shared__ int   kFin[RPB];

  const int t   = threadIdx.x;
  const int l   = t & 63;
  const int wv  = t >> 6;                    // 0..3 = code quarter
  const int col = l & 15;
  const int g   = l >> 4;
  const int B0  = blockIdx.x * RPB;          // all 4 waves share these 32 rows
  const int ph  = ((blockIdx.x * 4 + wv) * 7) & 15;   // per-WAVE phase

  // ---- x loads (8 independent float4; same rows for every wave) ----
  float4 xv[8];
  #pragma unroll
  for (int rt = 0; rt < 2; ++rt)
    #pragma unroll
    for (int kh = 0; kh < 2; ++kh) {
      const float* xp = x + (size_t)(B0 + rt * 16 + col) * DIM + kh * 32 + g * 8;
      xv[(rt * 2 + kh) * 2 + 0] = *(const float4*)xp;
      xv[(rt * 2 + kh) * 2 + 1] = *(const float4*)(xp + 4);
    }

  // ---- e2 -> LDS once (one barrier total, then barrier-free loop) ----
  #pragma unroll
  for (int i = 0; i < 4; ++i) e2L[t + i * 256] = e2h[t + i * 256];
  __syncthreads();

  // ---- split x -> fp16 (h,l) A-frags + Sum(x^2) over the 32 rows ----
  f16x8 a[2][2][2];     // [row-tile][k-half][h/l]
  float x2p = 0.f;
  #pragma unroll
  for (int rt = 0; rt < 2; ++rt)
    #pragma unroll
    for (int kh = 0; kh < 2; ++kh) {
      float4 v0 = xv[(rt * 2 + kh) * 2], v1 = xv[(rt * 2 + kh) * 2 + 1];
      float f[8] = {v0.x, v0.y, v0.z, v0.w, v1.x, v1.y, v1.z, v1.w};
      unsigned short hb[8], lb[8];
      #pragma unroll
      for (int j = 0; j < 8; ++j) {
        split2(f[j], hb[j], lb[j]);
        x2p = fmaf(f[j], f[j], x2p);
      }
      U4H uh; uh.u = pack8(hb); a[rt][kh][0] = uh.h;
      U4H ul; ul.u = pack8(lb); a[rt][kh][1] = ul.h;
    }
  #pragma unroll
  for (int off = 1; off < 64; off <<= 1) x2p += __shfl_xor(x2p, off, 64);

  float bestS[2][4];
  int   bestK[2][4];
  #pragma unroll
  for (int rt = 0; rt < 2; ++rt)
    #pragma unroll
    for (int r = 0; r < 4; ++r) { bestS[rt][r] = -3.402823466e38f; bestK[rt][r] = 0; }

  // ---- prefetch first tile of this wave's quarter into registers ----
  const unsigned short* ebl = eB + (size_t)(wv * 16) * 2048 + (size_t)l * 8;
  uint4 b0, b1, b2, b3;
  {
    const unsigned short* tp = ebl + (size_t)ph * 2048;
    b0 = *(const uint4*)(tp + 0 * 512);
    b1 = *(const uint4*)(tp + 1 * 512);
    b2 = *(const uint4*)(tp + 2 * 512);
    b3 = *(const uint4*)(tp + 3 * 512);
  }

  // ---- barrier-free main loop: 16 tiles, rotate prefetch, 12 MFMA/tile ----
  #pragma unroll 4
  for (int m = 0; m < 16; ++m) {
    const int ptn = (ph + m + 1) & 15;       // last iter reloads ph: harmless
    const unsigned short* tn = ebl + (size_t)ptn * 2048;
    uint4 n0 = *(const uint4*)(tn + 0 * 512);
    uint4 n1 = *(const uint4*)(tn + 1 * 512);
    uint4 n2 = *(const uint4*)(tn + 2 * 512);
    uint4 n3 = *(const uint4*)(tn + 3 * 512);

    const int pt  = (ph + m) & 15;
    const int kk0 = wv * 256 + pt * 16 + col;
    const float ne2 = -e2L[kk0];
    U4H q0, q1, q2, q3; q0.u = b0; q1.u = b1; q2.u = b2; q3.u = b3;
    #pragma unroll
    for (int rt = 0; rt < 2; ++rt) {
      f32x4 c0 = {ne2, ne2, ne2, ne2};
      f32x4 c1 = {0.f, 0.f, 0.f, 0.f};
      c0 = __builtin_amdgcn_mfma_f32_16x16x32_f16(a[rt][0][0], q0.h, c0, 0, 0, 0);
      c1 = __builtin_amdgcn_mfma_f32_16x16x32_f16(a[rt][1][0], q2.h, c1, 0, 0, 0);
      c0 = __builtin_amdgcn_mfma_f32_16x16x32_f16(a[rt][0][1], q0.h, c0, 0, 0, 0);
      c1 = __builtin_amdgcn_mfma_f32_16x16x32_f16(a[rt][1][1], q2.h, c1, 0, 0, 0);
      c0 = __builtin_amdgcn_mfma_f32_16x16x32_f16(a[rt][0][0], q1.h, c0, 0, 0, 0);
      c1 = __builtin_amdgcn_mfma_f32_16x16x32_f16(a[rt][1][0], q3.h, c1, 0, 0, 0);
      #pragma unroll
      for (int r = 0; r < 4; ++r) {
        float sv = c0[r] + c1[r];
        bool take = (sv > bestS[rt][r]) ||
                    (sv == bestS[rt][r] && kk0 < bestK[rt][r]);
        if (take) { bestS[rt][r] = sv; bestK[rt][r] = kk0; }
      }
    }
    b0 = n0; b1 = n1; b2 = n2; b3 = n3;
  }

  // ---- intra-wave argmax(S') merge over the 16 code-columns ----
  #pragma unroll
  for (int off = 1; off <= 8; off <<= 1) {
    #pragma unroll
    for (int rt = 0; rt < 2; ++rt)
      #pragma unroll
      for (int r = 0; r < 4; ++r) {
        float sp = __shfl_xor(bestS[rt][r], off, 64);
        int   kp = __shfl_xor(bestK[rt][r], off, 64);
        if (sp > bestS[rt][r] || (sp == bestS[rt][r] && kp < bestK[rt][r])) {
          bestS[rt][r] = sp; bestK[rt][r] = kp;
        }
      }
  }

  // col==0 lanes (g=0..3) hold this wave's quarter-minima for the 32 rows
  if (col == 0) {
    #pragma unroll
    for (int rt = 0; rt < 2; ++rt)
      #pragma unroll
      for (int r = 0; r < 4; ++r) {
        bestL[wv][rt * 16 + g * 4 + r] = bestS[rt][r];
        kL[wv][rt * 16 + g * 4 + r]    = bestK[rt][r];
      }
  }
  __syncthreads();

  // ---- cross-quarter merge (ascending wv = ascending codes; strict >) ----
  if (t < RPB) {
    float s = bestL[0][t]; int k = kL[0][t];
    #pragma unroll
    for (int q = 1; q < 4; ++q) {
      float s2 = bestL[q][t]; int k2 = kL[q][t];
      if (s2 > s) { s = s2; k = k2; }
    }
    kFin[t] = k;
    float v = s;                     // t<32 = lanes 0-31 of wave 0
    #pragma unroll
    for (int off = 1; off <= 16; off <<= 1) v += __shfl_xor(v, off, 64);
    if (t == 0)   // block loss: Sum d(32 rows) = Sum x^2 - 2*Sum S'best
      atomicAdd(loss, fmaf(-2.f, v, x2p) * (1.25f / (float)((size_t)NROWS * DIM)));
  }
  __syncthreads();

  // ---- cooperative gather-write: 8 threads/row, 8 floats each ----
  {
    const int row = t >> 3, seg = t & 7;
    const int bk = kFin[row];
    const float4* src = (const float4*)(e + (size_t)bk * DIM + seg * 8);
    float4* dst = (float4*)(out + (size_t)(B0 + row) * DIM + seg * 8);
    dst[0] = src[0];
    dst[1] = src[1];
  }
}

extern "C" void kernel_launch(void* const* d_in, const int* in_sizes, int n_in,
                              void* d_out, int out_size, void* d_ws, size_t ws_size,
                              hipStream_t stream) {
  const float* x = (const float*)d_in[0];   // [65536, 64]
  const float* e = (const float*)d_in[1];   // [1024, 64]
  float* out  = (float*)d_out;              // quantized_st [65536*64] + loss [1]
  float* loss = out + (size_t)NROWS * DIM;

  unsigned short* eB = (unsigned short*)d_ws;            // 64 tiles * 4 KB = 256 KB
  float* e2h = (float*)((char*)d_ws + 64 * 2048 * 2);    // 4 KB

  vq_esplit<<<NCODE / 256, 256, 0, stream>>>(e, eB, e2h, loss);
  vq_main  <<<NBLK, 256, 0, stream>>>(x, e, eB, e2h, out, loss);
}